// Round 2
// baseline (742.657 us; speedup 1.0000x reference)
//
#include <hip/hip_runtime.h>
#include <stdint.h>
#include <math.h>

#define IN_C 256
#define HID 128
#define OUT_C 64

// ---------------------------------------------------------------------------
// Preprocessing: degree, dinv, CSR build (dst-sorted adjacency)
// edge_index arrives as int32 (harness converts integer inputs to int*)
// ---------------------------------------------------------------------------

__global__ void init_kernel(float* __restrict__ degf, int* __restrict__ cnt, int n) {
    int i = blockIdx.x * blockDim.x + threadIdx.x;
    if (i < n) { degf[i] = 1.0f; cnt[i] = 1; }   // self-loop: weight 1, count 1
}

__global__ void deg_kernel(const int* __restrict__ ei, const float* __restrict__ ew,
                           float* __restrict__ degf, int* __restrict__ cnt, int e) {
    int j = blockIdx.x * blockDim.x + threadIdx.x;
    if (j < e) {
        int d = ei[e + j];
        atomicAdd(&degf[d], ew[j]);
        atomicAdd(&cnt[d], 1);
    }
}

__global__ void dinv_kernel(const float* __restrict__ degf, float* __restrict__ dinv, int n) {
    int i = blockIdx.x * blockDim.x + threadIdx.x;
    if (i < n) {
        float d = degf[i];
        dinv[i] = d > 0.f ? rsqrtf(d) : 0.f;
    }
}

// Single-block scan of cnt[] -> rowptr[] (inclusive into rowptr[i+1], exclusive into cursor[])
__global__ void scan_kernel(const int* __restrict__ cnt, int* __restrict__ rowptr,
                            int* __restrict__ cursor, int n) {
    __shared__ int wsum[16];
    const int tid = threadIdx.x;
    const int lane = tid & 63;
    const int wid = tid >> 6;
    int running = 0;
    for (int base = 0; base < n; base += 1024) {
        int i = base + tid;
        int v = (i < n) ? cnt[i] : 0;
        int incl = v;
        #pragma unroll
        for (int d = 1; d < 64; d <<= 1) {
            int t = __shfl_up(incl, d, 64);
            if (lane >= d) incl += t;
        }
        if (lane == 63) wsum[wid] = incl;
        __syncthreads();
        if (tid < 16) {
            int s = wsum[tid];
            #pragma unroll
            for (int d = 1; d < 16; d <<= 1) {
                int t = __shfl_up(s, d, 64);
                if (tid >= d) s += t;
            }
            wsum[tid] = s;
        }
        __syncthreads();
        int woff = running + (wid > 0 ? wsum[wid - 1] : 0);
        int inclusive = woff + incl;
        if (i < n) { rowptr[i + 1] = inclusive; cursor[i] = inclusive - v; }
        running += wsum[15];
        __syncthreads();
    }
    if (tid == 0) rowptr[0] = 0;
}

__global__ void fill_kernel(const int* __restrict__ ei, const float* __restrict__ ew,
                            const float* __restrict__ dinv, int* __restrict__ cursor,
                            int* __restrict__ col, float* __restrict__ val, int e, int n) {
    int j = blockIdx.x * blockDim.x + threadIdx.x;
    if (j < e) {
        int s = ei[j];
        int d = ei[e + j];
        float nv = dinv[s] * ew[j] * dinv[d];
        int pos = atomicAdd(&cursor[d], 1);
        col[pos] = s;
        val[pos] = nv;
    } else if (j < e + n) {
        int i = j - e;
        float dv = dinv[i];
        int pos = atomicAdd(&cursor[i], 1);
        col[pos] = i;
        val[pos] = dv * dv;
    }
}

// ---------------------------------------------------------------------------
// GEMM: O[n][128] = X[n][K] @ W[K][128]   (SPLIT: W = [Wa(Kx64) | Wb(Kx64)])
// block: 256 threads, 64 rows x 128 cols per block.
// In-place safe when O == X (each block fully reads its X rows into LDS
// across the k-loop before writing O rows; no cross-block row sharing).
// ---------------------------------------------------------------------------

template <int K, bool SPLIT>
__global__ __launch_bounds__(256) void gemm128_kernel(const float* __restrict__ X,
                                                      const float* __restrict__ Wa,
                                                      const float* __restrict__ Wb,
                                                      float* __restrict__ O, int n) {
    __shared__ float xs[64][33];
    __shared__ float ws[32][128];
    const int tid = threadIdx.x;
    const int rt = tid >> 5;   // 0..7
    const int ct = tid & 31;   // 0..31
    const int row0 = blockIdx.x * 64;

    float acc[8][4];
    #pragma unroll
    for (int r = 0; r < 8; ++r)
        #pragma unroll
        for (int j = 0; j < 4; ++j) acc[r][j] = 0.f;

    for (int k0 = 0; k0 < K; k0 += 32) {
        #pragma unroll
        for (int i = 0; i < 8; ++i) {
            int idx = tid + i * 256;
            int r = idx >> 5, kk = idx & 31;
            int row = row0 + r;
            xs[r][kk] = (row < n) ? X[(size_t)row * K + k0 + kk] : 0.f;
        }
        #pragma unroll
        for (int i = 0; i < 16; ++i) {
            int idx = tid + i * 256;
            int kr = idx >> 7, c = idx & 127;
            float w;
            if (SPLIT)
                w = (c < 64) ? Wa[(k0 + kr) * 64 + c] : Wb[(k0 + kr) * 64 + (c - 64)];
            else
                w = Wa[(k0 + kr) * 128 + c];
            ws[kr][c] = w;
        }
        __syncthreads();
        #pragma unroll
        for (int kk = 0; kk < 32; ++kk) {
            float wv[4];
            #pragma unroll
            for (int j = 0; j < 4; ++j) wv[j] = ws[kk][ct + 32 * j];
            #pragma unroll
            for (int rr = 0; rr < 8; ++rr) {
                float xv = xs[rt * 8 + rr][kk];
                #pragma unroll
                for (int j = 0; j < 4; ++j) acc[rr][j] += xv * wv[j];
            }
        }
        __syncthreads();
    }
    #pragma unroll
    for (int rr = 0; rr < 8; ++rr) {
        int row = row0 + rt * 8 + rr;
        if (row < n) {
            #pragma unroll
            for (int j = 0; j < 4; ++j) O[(size_t)row * 128 + ct + 32 * j] = acc[rr][j];
        }
    }
}

// ---------------------------------------------------------------------------
// Aggregation: one wave per node, float2 per lane (128 cols)
// ---------------------------------------------------------------------------

__global__ __launch_bounds__(256) void agg1_kernel(const int* __restrict__ rowptr,
                                                   const int* __restrict__ col,
                                                   const float* __restrict__ val,
                                                   const float* __restrict__ h0,
                                                   const float* __restrict__ b1,
                                                   float* __restrict__ h, int n) {
    const int lane = threadIdx.x & 63;
    const int node = blockIdx.x * 4 + (threadIdx.x >> 6);
    if (node >= n) return;
    const int start = rowptr[node];
    const int end = rowptr[node + 1];
    float2 acc = *(const float2*)&b1[2 * lane];
    int j = start;
    for (; j + 1 < end; j += 2) {
        int s0 = col[j], s1 = col[j + 1];
        float v0 = val[j], v1 = val[j + 1];
        float2 a = *(const float2*)&h0[(size_t)s0 * 128 + 2 * lane];
        float2 b = *(const float2*)&h0[(size_t)s1 * 128 + 2 * lane];
        acc.x += v0 * a.x + v1 * b.x;
        acc.y += v0 * a.y + v1 * b.y;
    }
    if (j < end) {
        int s0 = col[j];
        float v0 = val[j];
        float2 a = *(const float2*)&h0[(size_t)s0 * 128 + 2 * lane];
        acc.x += v0 * a.x;
        acc.y += v0 * a.y;
    }
    acc.x = acc.x > 0.f ? acc.x : expm1f(acc.x);
    acc.y = acc.y > 0.f ? acc.y : expm1f(acc.y);
    *(float2*)&h[(size_t)node * 128 + 2 * lane] = acc;
}

__global__ __launch_bounds__(256) void agg2_kernel(const int* __restrict__ rowptr,
                                                   const int* __restrict__ col,
                                                   const float* __restrict__ val,
                                                   const float* __restrict__ hcat,
                                                   const float* __restrict__ bmu,
                                                   const float* __restrict__ bls,
                                                   float* __restrict__ out, int n) {
    const int lane = threadIdx.x & 63;
    const int node = blockIdx.x * 4 + (threadIdx.x >> 6);
    if (node >= n) return;
    const int start = rowptr[node];
    const int end = rowptr[node + 1];
    const int ci = 2 * lane;  // 0..126
    float2 acc;
    if (lane < 32) acc = make_float2(bmu[ci], bmu[ci + 1]);
    else           acc = make_float2(bls[ci - 64], bls[ci - 63]);
    int j = start;
    for (; j + 1 < end; j += 2) {
        int s0 = col[j], s1 = col[j + 1];
        float v0 = val[j], v1 = val[j + 1];
        float2 a = *(const float2*)&hcat[(size_t)s0 * 128 + ci];
        float2 b = *(const float2*)&hcat[(size_t)s1 * 128 + ci];
        acc.x += v0 * a.x + v1 * b.x;
        acc.y += v0 * a.y + v1 * b.y;
    }
    if (j < end) {
        int s0 = col[j];
        float v0 = val[j];
        float2 a = *(const float2*)&hcat[(size_t)s0 * 128 + ci];
        acc.x += v0 * a.x;
        acc.y += v0 * a.y;
    }
    if (lane < 32)
        *(float2*)&out[(size_t)node * 64 + ci] = acc;
    else
        *(float2*)&out[(size_t)n * 64 + (size_t)node * 64 + (ci - 64)] = acc;
}

// ---------------------------------------------------------------------------

extern "C" void kernel_launch(void* const* d_in, const int* in_sizes, int n_in,
                              void* d_out, int out_size, void* d_ws, size_t ws_size,
                              hipStream_t stream) {
    const float* x   = (const float*)d_in[0];
    const int*   ei  = (const int*)d_in[1];      // int32 per harness convention
    const float* ew  = (const float*)d_in[2];
    const float* W1  = (const float*)d_in[3];
    const float* b1  = (const float*)d_in[4];
    const float* Wmu = (const float*)d_in[5];
    const float* bmu = (const float*)d_in[6];
    const float* Wls = (const float*)d_in[7];
    const float* bls = (const float*)d_in[8];
    float*       out = (float*)d_out;

    const int n = in_sizes[0] / IN_C;     // 50000
    const int e = in_sizes[2];            // 1600000

    char* ws = (char*)d_ws;
    size_t off = 0;
    auto alloc = [&](size_t bytes) -> void* {
        void* p = ws + off;
        off = (off + bytes + 255) & ~(size_t)255;
        return p;
    };
    float* degf   = (float*)alloc((size_t)n * 4);
    float* dinv   = (float*)alloc((size_t)n * 4);
    int*   cnt    = (int*)  alloc((size_t)n * 4);
    int*   rowptr = (int*)  alloc((size_t)(n + 1) * 4);
    int*   cursor = (int*)  alloc((size_t)n * 4);
    int*   col    = (int*)  alloc((size_t)(e + n) * 4);
    float* val    = (float*)alloc((size_t)(e + n) * 4);
    float* bufA   = (float*)alloc((size_t)n * 128 * 4);  // h0, later hcat (25.6 MB)
    (void)ws_size;
    // h (layer-1 activations, [n,128]) lives in d_out (== n*128 floats),
    // fully overwritten by agg2 at the end.
    float* hbuf = out;

    const int B = 256;
    init_kernel<<<(n + B - 1) / B, B, 0, stream>>>(degf, cnt, n);
    deg_kernel<<<(e + B - 1) / B, B, 0, stream>>>(ei, ew, degf, cnt, e);
    dinv_kernel<<<(n + B - 1) / B, B, 0, stream>>>(degf, dinv, n);
    scan_kernel<<<1, 1024, 0, stream>>>(cnt, rowptr, cursor, n);
    fill_kernel<<<(e + n + B - 1) / B, B, 0, stream>>>(ei, ew, dinv, cursor, col, val, e, n);

    // layer 1: h0 = x @ W1   (bufA)
    gemm128_kernel<IN_C, false><<<(n + 63) / 64, 256, 0, stream>>>(x, W1, nullptr, bufA, n);
    // h = elu(agg(h0) + b1)  (d_out as scratch)
    agg1_kernel<<<(n + 3) / 4, 256, 0, stream>>>(rowptr, col, val, bufA, b1, hbuf, n);
    // hcat = h @ [Wmu | Wls]  (bufA)
    gemm128_kernel<HID, true><<<(n + 63) / 64, 256, 0, stream>>>(hbuf, Wmu, Wls, bufA, n);
    // mu/logstd = agg(hcat) + bias  (final d_out)
    agg2_kernel<<<(n + 3) / 4, 256, 0, stream>>>(rowptr, col, val, bufA, bmu, bls, out, n);
}

// Round 3
// 644.044 us; speedup vs baseline: 1.1531x; 1.1531x over previous
//
#include <hip/hip_runtime.h>
#include <stdint.h>
#include <math.h>

#define IN_C 256
#define HID 128
#define OUT_C 64

// CSR entry: .x = __int_as_float(src col), .y = edge value
// ---------------------------------------------------------------------------
// Preprocessing
// ---------------------------------------------------------------------------

__global__ void init_kernel(int* __restrict__ cnt, int n) {
    int i = blockIdx.x * blockDim.x + threadIdx.x;
    if (i < n) cnt[i] = 1;   // self-loop
}

__global__ void count_kernel(const int* __restrict__ ei, int* __restrict__ cnt, int e) {
    int j = blockIdx.x * blockDim.x + threadIdx.x;
    if (j < e) atomicAdd(&cnt[ei[e + j]], 1);
}

// ---- 3-kernel parallel scan: cnt[0..n) -> rowptr[n+1], cursor[n] ----------

__global__ __launch_bounds__(256) void scanA_kernel(const int* __restrict__ cnt,
                                                    int* __restrict__ bsum, int n) {
    __shared__ int wsum[4];
    int i = blockIdx.x * 256 + threadIdx.x;
    int v = (i < n) ? cnt[i] : 0;
    const int lane = threadIdx.x & 63, wid = threadIdx.x >> 6;
    #pragma unroll
    for (int d = 1; d < 64; d <<= 1) {
        int t = __shfl_up(v, d, 64);
        if (lane >= d) v += t;
    }
    if (lane == 63) wsum[wid] = v;
    __syncthreads();
    if (threadIdx.x == 0) bsum[blockIdx.x] = wsum[0] + wsum[1] + wsum[2] + wsum[3];
}

__global__ __launch_bounds__(256) void scanB_kernel(int* __restrict__ bsum, int nb) {
    __shared__ int wsum[4];
    const int tid = threadIdx.x, lane = tid & 63, wid = tid >> 6;
    int v = (tid < nb) ? bsum[tid] : 0;
    int incl = v;
    #pragma unroll
    for (int d = 1; d < 64; d <<= 1) {
        int t = __shfl_up(incl, d, 64);
        if (lane >= d) incl += t;
    }
    if (lane == 63) wsum[wid] = incl;
    __syncthreads();
    int woff = 0;
    for (int w = 0; w < wid; ++w) woff += wsum[w];
    if (tid < nb) bsum[tid] = woff + incl - v;   // exclusive
}

__global__ __launch_bounds__(256) void scanC_kernel(const int* __restrict__ cnt,
                                                    const int* __restrict__ bsum,
                                                    int* __restrict__ rowptr,
                                                    int* __restrict__ cursor, int n) {
    __shared__ int wsum[4];
    int i = blockIdx.x * 256 + threadIdx.x;
    int v = (i < n) ? cnt[i] : 0;
    const int lane = threadIdx.x & 63, wid = threadIdx.x >> 6;
    int incl = v;
    #pragma unroll
    for (int d = 1; d < 64; d <<= 1) {
        int t = __shfl_up(incl, d, 64);
        if (lane >= d) incl += t;
    }
    if (lane == 63) wsum[wid] = incl;
    __syncthreads();
    int woff = bsum[blockIdx.x];
    for (int w = 0; w < wid; ++w) woff += wsum[w];
    if (i < n) {
        int excl = woff + incl - v;
        cursor[i] = excl;
        rowptr[i + 1] = excl + v;
    }
    if (i == 0) rowptr[0] = 0;
}

// ---- scatter edges (raw weight) into CSR ----------------------------------

__global__ void fill_kernel(const int* __restrict__ ei, const float* __restrict__ ew,
                            int* __restrict__ cursor, float2* __restrict__ pairs,
                            int e, int n) {
    int j = blockIdx.x * blockDim.x + threadIdx.x;
    if (j < e) {
        int s = ei[j];
        int d = ei[e + j];
        int pos = atomicAdd(&cursor[d], 1);
        pairs[pos] = make_float2(__int_as_float(s), ew[j]);
    } else if (j < e + n) {
        int i = j - e;
        int pos = atomicAdd(&cursor[i], 1);
        pairs[pos] = make_float2(__int_as_float(i), 1.0f);
    }
}

// ---- weighted degree per row (segmented sum), dinv = rsqrt ----------------

__global__ __launch_bounds__(256) void rowsum_kernel(const int* __restrict__ rowptr,
                                                     const float2* __restrict__ pairs,
                                                     float* __restrict__ dinv, int n) {
    const int l = threadIdx.x & 15;
    const int node = blockIdx.x * 16 + (threadIdx.x >> 4);
    if (node >= n) return;
    const int start = rowptr[node], end = rowptr[node + 1];
    float sum = 0.f;
    for (int k = start + l; k < end; k += 16) sum += pairs[k].y;
    #pragma unroll
    for (int d = 1; d < 16; d <<= 1) sum += __shfl_xor(sum, d, 64);
    if (l == 0) dinv[node] = rsqrtf(sum);   // sum >= 1 (self-loop) > 0
}

// ---- val[k] *= dinv[col[k]] ----------------------------------------------

__global__ void fixup_kernel(float2* __restrict__ pairs, const float* __restrict__ dinv,
                             int nnz) {
    int k = blockIdx.x * blockDim.x + threadIdx.x;
    if (k < nnz) {
        float2 p = pairs[k];
        p.y *= dinv[__float_as_int(p.x)];
        pairs[k] = p;
    }
}

// ---------------------------------------------------------------------------
// GEMM: O[n][128] = X[n][K] @ W[K][128]   (SPLIT: W = [Wa(Kx64) | Wb(Kx64)])
// ---------------------------------------------------------------------------

template <int K, bool SPLIT>
__global__ __launch_bounds__(256) void gemm128_kernel(const float* __restrict__ X,
                                                      const float* __restrict__ Wa,
                                                      const float* __restrict__ Wb,
                                                      float* __restrict__ O, int n) {
    __shared__ float xs[64][33];
    __shared__ float ws[32][128];
    const int tid = threadIdx.x;
    const int rt = tid >> 5;   // 0..7
    const int ct = tid & 31;   // 0..31
    const int row0 = blockIdx.x * 64;

    float acc[8][4];
    #pragma unroll
    for (int r = 0; r < 8; ++r)
        #pragma unroll
        for (int j = 0; j < 4; ++j) acc[r][j] = 0.f;

    for (int k0 = 0; k0 < K; k0 += 32) {
        #pragma unroll
        for (int i = 0; i < 8; ++i) {
            int idx = tid + i * 256;
            int r = idx >> 5, kk = idx & 31;
            int row = row0 + r;
            xs[r][kk] = (row < n) ? X[(size_t)row * K + k0 + kk] : 0.f;
        }
        #pragma unroll
        for (int i = 0; i < 16; ++i) {
            int idx = tid + i * 256;
            int kr = idx >> 7, c = idx & 127;
            float w;
            if (SPLIT)
                w = (c < 64) ? Wa[(k0 + kr) * 64 + c] : Wb[(k0 + kr) * 64 + (c - 64)];
            else
                w = Wa[(k0 + kr) * 128 + c];
            ws[kr][c] = w;
        }
        __syncthreads();
        #pragma unroll
        for (int kk = 0; kk < 32; ++kk) {
            float wv[4];
            #pragma unroll
            for (int j = 0; j < 4; ++j) wv[j] = ws[kk][ct + 32 * j];
            #pragma unroll
            for (int rr = 0; rr < 8; ++rr) {
                float xv = xs[rt * 8 + rr][kk];
                #pragma unroll
                for (int j = 0; j < 4; ++j) acc[rr][j] += xv * wv[j];
            }
        }
        __syncthreads();
    }
    #pragma unroll
    for (int rr = 0; rr < 8; ++rr) {
        int row = row0 + rt * 8 + rr;
        if (row < n) {
            #pragma unroll
            for (int j = 0; j < 4; ++j) O[(size_t)row * 128 + ct + 32 * j] = acc[rr][j];
        }
    }
}

// ---------------------------------------------------------------------------
// Aggregation: one wave per node, float2 per lane (128 cols)
// out_row = dinv[node] * sum_k val_k * h[col_k]  + bias
// ---------------------------------------------------------------------------

__global__ __launch_bounds__(256) void agg1_kernel(const int* __restrict__ rowptr,
                                                   const float2* __restrict__ pairs,
                                                   const float* __restrict__ dinv,
                                                   const float* __restrict__ h0,
                                                   const float* __restrict__ b1,
                                                   float* __restrict__ h, int n) {
    const int lane = threadIdx.x & 63;
    const int node = blockIdx.x * 4 + (threadIdx.x >> 6);
    if (node >= n) return;
    const int start = rowptr[node];
    const int end = rowptr[node + 1];
    float2 acc = make_float2(0.f, 0.f);
    int j = start;
    for (; j + 1 < end; j += 2) {
        float2 p0 = pairs[j], p1 = pairs[j + 1];
        int s0 = __float_as_int(p0.x), s1 = __float_as_int(p1.x);
        float2 a = *(const float2*)&h0[(size_t)s0 * 128 + 2 * lane];
        float2 b = *(const float2*)&h0[(size_t)s1 * 128 + 2 * lane];
        acc.x += p0.y * a.x + p1.y * b.x;
        acc.y += p0.y * a.y + p1.y * b.y;
    }
    if (j < end) {
        float2 p0 = pairs[j];
        int s0 = __float_as_int(p0.x);
        float2 a = *(const float2*)&h0[(size_t)s0 * 128 + 2 * lane];
        acc.x += p0.y * a.x;
        acc.y += p0.y * a.y;
    }
    const float dn = dinv[node];
    float2 bb = *(const float2*)&b1[2 * lane];
    acc.x = dn * acc.x + bb.x;
    acc.y = dn * acc.y + bb.y;
    acc.x = acc.x > 0.f ? acc.x : expm1f(acc.x);
    acc.y = acc.y > 0.f ? acc.y : expm1f(acc.y);
    *(float2*)&h[(size_t)node * 128 + 2 * lane] = acc;
}

__global__ __launch_bounds__(256) void agg2_kernel(const int* __restrict__ rowptr,
                                                   const float2* __restrict__ pairs,
                                                   const float* __restrict__ dinv,
                                                   const float* __restrict__ hcat,
                                                   const float* __restrict__ bmu,
                                                   const float* __restrict__ bls,
                                                   float* __restrict__ out, int n) {
    const int lane = threadIdx.x & 63;
    const int node = blockIdx.x * 4 + (threadIdx.x >> 6);
    if (node >= n) return;
    const int start = rowptr[node];
    const int end = rowptr[node + 1];
    const int ci = 2 * lane;  // 0..126
    float2 acc = make_float2(0.f, 0.f);
    int j = start;
    for (; j + 1 < end; j += 2) {
        float2 p0 = pairs[j], p1 = pairs[j + 1];
        int s0 = __float_as_int(p0.x), s1 = __float_as_int(p1.x);
        float2 a = *(const float2*)&hcat[(size_t)s0 * 128 + ci];
        float2 b = *(const float2*)&hcat[(size_t)s1 * 128 + ci];
        acc.x += p0.y * a.x + p1.y * b.x;
        acc.y += p0.y * a.y + p1.y * b.y;
    }
    if (j < end) {
        float2 p0 = pairs[j];
        int s0 = __float_as_int(p0.x);
        float2 a = *(const float2*)&hcat[(size_t)s0 * 128 + ci];
        acc.x += p0.y * a.x;
        acc.y += p0.y * a.y;
    }
    const float dn = dinv[node];
    if (lane < 32) {
        acc.x = dn * acc.x + bmu[ci];
        acc.y = dn * acc.y + bmu[ci + 1];
        *(float2*)&out[(size_t)node * 64 + ci] = acc;
    } else {
        acc.x = dn * acc.x + bls[ci - 64];
        acc.y = dn * acc.y + bls[ci - 63];
        *(float2*)&out[(size_t)n * 64 + (size_t)node * 64 + (ci - 64)] = acc;
    }
}

// ---------------------------------------------------------------------------

extern "C" void kernel_launch(void* const* d_in, const int* in_sizes, int n_in,
                              void* d_out, int out_size, void* d_ws, size_t ws_size,
                              hipStream_t stream) {
    const float* x   = (const float*)d_in[0];
    const int*   ei  = (const int*)d_in[1];
    const float* ew  = (const float*)d_in[2];
    const float* W1  = (const float*)d_in[3];
    const float* b1  = (const float*)d_in[4];
    const float* Wmu = (const float*)d_in[5];
    const float* bmu = (const float*)d_in[6];
    const float* Wls = (const float*)d_in[7];
    const float* bls = (const float*)d_in[8];
    float*       out = (float*)d_out;

    const int n = in_sizes[0] / IN_C;     // 50000
    const int e = in_sizes[2];            // 1600000
    const int nnz = e + n;

    char* ws = (char*)d_ws;
    size_t off = 0;
    auto alloc = [&](size_t bytes) -> void* {
        void* p = ws + off;
        off = (off + bytes + 255) & ~(size_t)255;
        return p;
    };
    int*    cnt    = (int*)   alloc((size_t)n * 4);
    int*    rowptr = (int*)   alloc((size_t)(n + 1) * 4);
    int*    cursor = (int*)   alloc((size_t)n * 4);
    int*    bsum   = (int*)   alloc(1024 * 4);
    float*  dinv   = (float*) alloc((size_t)n * 4);
    float2* pairs  = (float2*)alloc((size_t)nnz * 8);
    float*  bufA   = (float*) alloc((size_t)n * 128 * 4);  // h0, later hcat
    (void)ws_size;
    float* hbuf = out;   // layer-1 activations live in d_out, overwritten at end

    const int B = 256;
    const int nb = (n + 255) / 256;
    init_kernel<<<(n + B - 1) / B, B, 0, stream>>>(cnt, n);
    count_kernel<<<(e + B - 1) / B, B, 0, stream>>>(ei, cnt, e);
    scanA_kernel<<<nb, 256, 0, stream>>>(cnt, bsum, n);
    scanB_kernel<<<1, 256, 0, stream>>>(bsum, nb);
    scanC_kernel<<<nb, 256, 0, stream>>>(cnt, bsum, rowptr, cursor, n);
    fill_kernel<<<(nnz + B - 1) / B, B, 0, stream>>>(ei, ew, cursor, pairs, e, n);
    rowsum_kernel<<<(n + 15) / 16, 256, 0, stream>>>(rowptr, pairs, dinv, n);
    fixup_kernel<<<(nnz + B - 1) / B, B, 0, stream>>>(pairs, dinv, nnz);

    gemm128_kernel<IN_C, false><<<(n + 63) / 64, 256, 0, stream>>>(x, W1, nullptr, bufA, n);
    agg1_kernel<<<(n + 3) / 4, 256, 0, stream>>>(rowptr, pairs, dinv, bufA, b1, hbuf, n);
    gemm128_kernel<HID, true><<<(n + 63) / 64, 256, 0, stream>>>(hbuf, Wmu, Wls, bufA, n);
    agg2_kernel<<<(n + 3) / 4, 256, 0, stream>>>(rowptr, pairs, dinv, bufA, bmu, bls, out, n);
}